// Round 3
// baseline (126.343 us; speedup 1.0000x reference)
//
#include <hip/hip_runtime.h>
#include <math.h>

#define BB 32
#define SV 4096
#define SQ 1152
#define DD 128
#define FD 96
#define NS 8                       // chunks over SV
#define RPC (SV / NS)              // 512 rows per chunk
#define LOG2E 1.44269504088896340f

// ---- workspace layout (float offsets) ----
// G: [B,D,FD] group-of-12 sums of q        393216 floats
// P: [B,NS,6,D] partial v moments M1..M6   196608 floats
#define OFF_G    0
#define OFF_P    393216
#define OFF_ATT0 589824
#define OFF_LI   593920
#define OFF_A0   593952
#define OFF_A0S  593984
#define OFF_IP   594016

// K1 (fused): blocks [0,256): v -> moment partials; blocks [256,1792): q -> G.
__global__ __launch_bounds__(256) void k_pass1(const float* __restrict__ q,
                                               const float* __restrict__ v,
                                               float* __restrict__ ws) {
    __shared__ float red[6][8][DD];   // 24 KB (v-branch only)
    if (blockIdx.x < 256) {
        int b = blockIdx.x >> 3, chunk = blockIdx.x & 7;
        int lane = threadIdx.x & 31, rowg = threadIdx.x >> 5;   // 8 rows in flight
        int d0 = lane * 4;
        const float* base = v + ((size_t)b * SV + (size_t)chunk * RPC) * DD;
        float s1[4] = {}, s2[4] = {}, s3[4] = {}, s4[4] = {}, s5[4] = {}, s6[4] = {};
        for (int i = 0; i < RPC / 8; i++) {
            float4 x = *reinterpret_cast<const float4*>(base + (size_t)(rowg + 8 * i) * DD + d0);
            float vv[4] = {x.x, x.y, x.z, x.w};
#pragma unroll
            for (int j = 0; j < 4; j++) {
                float a = vv[j], a2 = a * a, a4 = a2 * a2;
                s1[j] += a;       s2[j] += a2;      s3[j] += a2 * a;
                s4[j] += a4;      s5[j] += a4 * a;  s6[j] += a4 * a2;
            }
        }
#pragma unroll
        for (int j = 0; j < 4; j++) {
            red[0][rowg][d0 + j] = s1[j]; red[1][rowg][d0 + j] = s2[j];
            red[2][rowg][d0 + j] = s3[j]; red[3][rowg][d0 + j] = s4[j];
            red[4][rowg][d0 + j] = s5[j]; red[5][rowg][d0 + j] = s6[j];
        }
        __syncthreads();
        for (int t = threadIdx.x; t < 6 * DD; t += 256) {
            int m = t >> 7, d = t & (DD - 1);
            float a = 0;
#pragma unroll
            for (int r = 0; r < 8; r++) a += red[m][r][d];
            ws[OFF_P + ((size_t)(b * NS + chunk) * 6 + m) * DD + d] = a;
        }
    } else {
        int g = (blockIdx.x - 256) * 256 + threadIdx.x;   // 0..393215
        const float4* p = reinterpret_cast<const float4*>(q + (size_t)g * 12);
        float4 a = p[0], b4 = p[1], c = p[2];
        ws[OFF_G + g] = ((a.x + a.y) + (a.z + a.w)) + ((b4.x + b4.y) + (b4.z + b4.w))
                      + ((c.x + c.y) + (c.z + c.w));
    }
}

// K2: per-batch finalize. One block per b, 1024 threads.
__global__ __launch_bounds__(1024) void k_finalize(const float* __restrict__ v,
                                                   const float* __restrict__ hmat,
                                                   const float* __restrict__ hbias,
                                                   float* __restrict__ ws) {
    int b = blockIdx.x, tid = threadIdx.x;
    __shared__ float Gl[DD * 97];                  // 48.5 KB, padded vs 96%32==0
    __shared__ float Ml[6][DD];                    // Ml[0] doubles as sv
    __shared__ float qsl[DD];
    __shared__ float pp[8][FD];
    __shared__ float hm_l[3], hb_l[3];
    __shared__ float redc[10];
    __shared__ float sumq_sh;
    // prefetch the three v rows we need (latency-hidden under staging)
    float v0 = 0, v1 = 0, v2 = 0;
    if (tid < DD) {
        v0 = v[((size_t)b * SV + 0) * DD + tid];
        v1 = v[((size_t)b * SV + 1) * DD + tid];
        v2 = v[((size_t)b * SV + 2) * DD + tid];
    }
    // ---- phase A (all independent): stage G, reduce moments, hm/hb ----
    const float* Gb = ws + OFF_G + (size_t)b * DD * FD;
#pragma unroll
    for (int i = 0; i < 3; i++) {
        int idx = (i * 1024 + tid) * 4;
        float4 x = *reinterpret_cast<const float4*>(Gb + idx);
        float xv[4] = {x.x, x.y, x.z, x.w};
#pragma unroll
        for (int j = 0; j < 4; j++) {
            int e = idx + j, dd = e / 96, f = e - dd * 96;
            Gl[dd * 97 + f] = xv[j];
        }
    }
    if (tid < 6 * DD) {                            // 768 (m,d) reduces of 8 chunks
        int m = tid >> 7, d = tid & (DD - 1);
        const float* p = ws + OFF_P + (size_t)b * NS * 6 * DD + m * DD + d;
        float a = 0;
#pragma unroll
        for (int ch = 0; ch < NS; ch++) a += p[(size_t)ch * 6 * DD];
        Ml[m][d] = a;
    } else if (tid >= 768 && tid < 864) {          // hm: 32 lanes per c
        int t2 = tid - 768, c = t2 >> 5, x = t2 & 31;
        float h = hmat[c * FD + x] + hmat[c * FD + x + 32] + hmat[c * FD + x + 64];
        h += __shfl_xor(h, 1, 64); h += __shfl_xor(h, 2, 64);
        h += __shfl_xor(h, 4, 64); h += __shfl_xor(h, 8, 64); h += __shfl_xor(h, 16, 64);
        if (x == 0) { hm_l[c] = h; hb_l[c] = hbias[c]; }
    }
    __syncthreads();
    // ---- phase B: qs row sums from LDS (8 threads per row) ----
    {
        int row = tid >> 3, j = tid & 7;
        const float* gr = &Gl[row * 97 + j * 12];
        float x = 0;
#pragma unroll
        for (int i = 0; i < 12; i++) x += gr[i];
        x += __shfl_xor(x, 1, 64); x += __shfl_xor(x, 2, 64); x += __shfl_xor(x, 4, 64);
        if (j == 0) qsl[row] = x;
    }
    __syncthreads();
    // ---- phase C: sumq ----
    if (tid < 64) {
        float x = qsl[tid] + qsl[tid + 64];
#pragma unroll
        for (int ofs = 32; ofs; ofs >>= 1) x += __shfl_xor(x, ofs, 64);
        if (tid == 0) sumq_sh = x;
    }
    __syncthreads();
    // ---- phase D: att at s=0,1,2 + per-batch scalar partials ----
    if (tid < DD) {
        float sumq = sumq_sh;
        float M1 = Ml[0][tid], M2 = Ml[1][tid], M3 = Ml[2][tid];
        float M4 = Ml[3][tid], M5 = Ml[4][tid], M6 = Ml[5][tid];
        float att0 = 0, att1 = 0, att2 = 0;
#pragma unroll
        for (int c = 0; c < 3; c++) {
            float alpha = hm_l[c] * sumq, hb = hb_l[c];
            float n2 = alpha * alpha * M2 + 2.f * alpha * hb * M1 + (float)SV * hb * hb;
            float tt = alpha / sqrtf(n2);          // |tt*v| <= ~0.1 -> Taylor-safe
            float Z = (float)SV + tt * (M1 + tt * (0.5f * M2 + tt * ((1.f / 6.f) * M3
                    + tt * ((1.f / 24.f) * M4 + tt * ((1.f / 120.f) * M5
                    + tt * (1.f / 720.f) * M6)))));
            float rz = 1.f / Z, tl = tt * LOG2E;
            att0 += exp2f(v0 * tl) * rz;
            att1 += exp2f(v1 * tl) * rz;
            att2 += exp2f(v2 * tl) * rz;
        }
        ws[OFF_ATT0 + b * DD + tid] = att0;
        float qsv = qsl[tid];
        float vals[5] = {att0, att0 * att0, att1 * qsv, att2 * qsv, M1};
#pragma unroll
        for (int i = 0; i < 5; i++) {
            float x = vals[i];
#pragma unroll
            for (int ofs = 32; ofs; ofs >>= 1) x += __shfl_xor(x, ofs, 64);
            if ((tid & 63) == 0) redc[(tid >> 6) * 5 + i] = x;
        }
    }
    __syncthreads();
    // ---- phase E: ip GEMV partials + per-batch finals ----
    if (tid < 8 * FD) {
        int kc = tid / FD, f = tid - kc * FD;
        float s = 0;
#pragma unroll
        for (int k0 = 0; k0 < 16; k0++) {
            int k = kc * 16 + k0;
            s += Ml[0][k] * Gl[k * 97 + f];
        }
        pp[kc][f] = s;
    } else if (tid == 1023) {
        float a0 = redc[0] + redc[5], a0s = redc[1] + redc[6];
        float r1 = redc[2] + redc[7], r2 = redc[3] + redc[8], vs = redc[4] + redc[9];
        ws[OFF_A0 + b] = a0; ws[OFF_A0S + b] = a0s;
        ws[OFF_LI + b] = vs * (r1 + r2);           // l1 + l2
    }
    __syncthreads();
    if (tid < FD) {
        float s = 0;
#pragma unroll
        for (int r = 0; r < 8; r++) s += pp[r][tid];
        ws[OFF_IP + b * FD + tid] = s * (1.0f / 12.0f);
    }
}

// K3: fused BatchNorm stats (closed form, per-f in parallel) + output write.
// One block per batch; every block recomputes the 96 channel stats (cheap, L2-hot).
__global__ __launch_bounds__(256) void k_out(const float* __restrict__ gamma,
                                             const float* __restrict__ beta,
                                             const float* __restrict__ ws,
                                             float* __restrict__ out) {
    int b = blockIdx.x, tid = threadIdx.x;
    __shared__ float att0l[DD], ipl[FD], bnAl[FD], bnBl[FD];
    __shared__ float li_sh;
    if (tid < DD) att0l[tid] = ws[OFF_ATT0 + b * DD + tid];
    else if (tid < DD + FD) ipl[tid - DD] = ws[OFF_IP + b * FD + (tid - DD)];
    if (tid == DD + FD) li_sh = ws[OFF_LI + b];
    if (tid < FD) {
        const float* ipb = ws + OFF_IP; const float* A0b = ws + OFF_A0;
        const float* A0sb = ws + OFF_A0S; const float* lib = ws + OFF_LI;
        double Sm = 0, Se2 = 0, Sl = 0;
#pragma unroll 4
        for (int bb = 0; bb < BB; bb++) {
            double ip = ipb[bb * FD + tid], a0 = A0b[bb], a0s = A0sb[bb], l = lib[bb];
            Sm += ip * a0;
            Se2 += ip * ip * a0s + 2.0 * ip * l * a0 + (double)DD * l * l;
            Sl += l;
        }
        double mean = Sm / ((double)BB * DD) + Sl / (double)BB;
        double var = Se2 / ((double)BB * DD) - mean * mean;
        double rstd = 1.0 / sqrt(var + 1e-5);
        float A = (float)rstd * gamma[tid];
        bnAl[tid] = A; bnBl[tid] = beta[tid] - (float)mean * A;
    }
    __syncthreads();
    float li = li_sh;
#pragma unroll
    for (int i = 0; i < 12; i++) {
        int o = (i * 256 + tid) * 4;
        int f = o >> 7, k = o & (DD - 1);
        float A = bnAl[f], Bc = bnBl[f], ip = ipl[f];
        float base = li * A + Bc, scale = ip * A;
        float4 av = *reinterpret_cast<const float4*>(&att0l[k]);
        float4 r;
        r.x = av.x * scale + base; r.y = av.y * scale + base;
        r.z = av.z * scale + base; r.w = av.w * scale + base;
        *reinterpret_cast<float4*>(out + (size_t)b * FD * DD + o) = r;
    }
}

extern "C" void kernel_launch(void* const* d_in, const int* in_sizes, int n_in,
                              void* d_out, int out_size, void* d_ws, size_t ws_size,
                              hipStream_t stream) {
    const float* q     = (const float*)d_in[0];
    const float* v     = (const float*)d_in[1];
    const float* hmat  = (const float*)d_in[2];
    const float* hbias = (const float*)d_in[3];
    const float* gamma = (const float*)d_in[4];
    const float* beta  = (const float*)d_in[5];
    float* out = (float*)d_out;
    float* ws = (float*)d_ws;

    k_pass1<<<1792, 256, 0, stream>>>(q, v, ws);
    k_finalize<<<BB, 1024, 0, stream>>>(v, hmat, hbias, ws);
    k_out<<<BB, 256, 0, stream>>>(gamma, beta, ws, out);
}